// Round 7
// baseline (23.338 us; speedup 1.0000x reference)
//
#include <hip/hip_runtime.h>

// x: (N=64, C=3, W=16, T=128, V=25, M=2) fp32, row-major
// strides (elems): N:307200, C:102400, W:6400, T:50, V:2, M:1
// b = ((n*T+t)*V+v)*M+m ; local = t*50+v*2+m == b % 6400 (bijective, order-preserving)
// xr[c][w] = flat elem i = c*16+w of permuted (W,C) block -> (c_orig,w_orig)=(i%3,i/3)
// R7: 4 b/thread float4 loads -> per (c,w) slice each block touches 4KB contiguous
// (DRAM row-burst locality), combined with load-all-first ILP (R6's windowed regs).
// R4 had 4KB bursts but fused loads (vmcnt-serialized); R6 had ILP but 1KB bursts.
// Single-pass moments: cov = (Sxy - 16*mx*my)/15.
// Epilogue: stage 32KB block output in LDS (XOR-swizzled), lane-contiguous float4 stores.
// out: (B,4,4) fp32, B = 409600.  Grid exact: 800 blocks x 128 threads.

__global__ void __launch_bounds__(128)
gaussian_embed_kernel(const float* __restrict__ x, float* __restrict__ out) {
    __shared__ float4 lds[2048];  // 128 threads * 16 float4 = 32KB

    const int t  = threadIdx.x;
    const int tb = blockIdx.x * 128 + t;
    const int b  = tb << 2;
    const int n   = b / 6400;
    const int rem = b - n * 6400;
    // float4-unit strides: c_orig: 102400/4=25600, w_orig: 6400/4=1600
    const float4* __restrict__ xb = (const float4*)(x + (size_t)n * 307200 + rem);

    // ---- Phase 1: issue all 48 float4 loads (grouped by w = consume order);
    // compiler windows the 192-reg buffer via live-range shrinking.
    float4 rr[16][3];
#pragma unroll
    for (int w = 0; w < 16; ++w) {
#pragma unroll
        for (int c = 0; c < 3; ++c) {
            const int i = c * 16 + w;  // flat xr index
            rr[w][c] = xb[(i % 3) * 25600 + (i / 3) * 1600];
        }
    }

    // ---- Phase 2: single-pass moments
    float s0[4] = {0,0,0,0}, s1[4] = {0,0,0,0}, s2[4] = {0,0,0,0};
    float p00[4] = {0,0,0,0}, p01[4] = {0,0,0,0}, p02[4] = {0,0,0,0};
    float p11[4] = {0,0,0,0}, p12[4] = {0,0,0,0}, p22[4] = {0,0,0,0};
#pragma unroll
    for (int w = 0; w < 16; ++w) {
        const float a[4]  = {rr[w][0].x, rr[w][0].y, rr[w][0].z, rr[w][0].w};
        const float bb[4] = {rr[w][1].x, rr[w][1].y, rr[w][1].z, rr[w][1].w};
        const float cc[4] = {rr[w][2].x, rr[w][2].y, rr[w][2].z, rr[w][2].w};
#pragma unroll
        for (int j = 0; j < 4; ++j) {
            s0[j]  += a[j];          s1[j]  += bb[j];          s2[j]  += cc[j];
            p00[j] += a[j] * a[j];   p01[j] += a[j] * bb[j];   p02[j] += a[j] * cc[j];
            p11[j] += bb[j] * bb[j]; p12[j] += bb[j] * cc[j];  p22[j] += cc[j] * cc[j];
        }
    }

    // ---- Phase 3: epilogue per b
#pragma unroll
    for (int j = 0; j < 4; ++j) {
        const float m0 = s0[j] * 0.0625f, m1 = s1[j] * 0.0625f, m2 = s2[j] * 0.0625f;
        const float inv15 = 1.f / 15.f;
        const float c00 = (p00[j] - 16.f * m0 * m0) * inv15;
        const float c01 = (p01[j] - 16.f * m0 * m1) * inv15;
        const float c02 = (p02[j] - 16.f * m0 * m2) * inv15;
        const float c11 = (p11[j] - 16.f * m1 * m1) * inv15;
        const float c12 = (p12[j] - 16.f * m1 * m2) * inv15;
        const float c22 = (p22[j] - 16.f * m2 * m2) * inv15;

        const float tr    = c00 + c11 + c22;
        const float invtr = 1.f / tr;
        const float diag  = 0.001f * tr;
        const float a  = c00 * invtr + diag;
        const float bq = c01 * invtr;
        const float cq = c02 * invtr;
        const float d  = c11 * invtr + diag;
        const float e  = c12 * invtr;
        const float g  = c22 * invtr + diag;

        const float det = a * (d * g - e * e) - bq * (bq * g - cq * e) + cq * (bq * e - cq * d);
        const float dsp = rsqrtf(sqrtf(det));  // det^(-1/4)

        const float om01 = dsp * (bq + m0 * m1);
        const float om02 = dsp * (cq + m0 * m2);
        const float om12 = dsp * (e + m1 * m2);
        const float dm0 = dsp * m0, dm1 = dsp * m1, dm2 = dsp * m2;

        // Stage 4 rows (float4 each) into LDS, XOR-swizzled: slot = j*4 + row
        const int base = t * 16;
        const int sw   = t & 15;
        lds[base + ((j * 4 + 0) ^ sw)] = make_float4(dsp * (a + m0 * m0), om01, om02, dm0);
        lds[base + ((j * 4 + 1) ^ sw)] = make_float4(om01, dsp * (d + m1 * m1), om12, dm1);
        lds[base + ((j * 4 + 2) ^ sw)] = make_float4(om02, om12, dsp * (g + m2 * m2), dm2);
        lds[base + ((j * 4 + 3) ^ sw)] = make_float4(dm0, dm1, dm2, dsp);
    }

    __syncthreads();

    // ---- Phase 4: coalesced block store (block covers 2048 float4 = 32KB contiguous)
    float4* __restrict__ o = (float4*)out + (size_t)blockIdx.x * 2048;
#pragma unroll
    for (int k2 = 0; k2 < 16; ++k2) {
        const int g  = k2 * 128 + t;
        const int ts = g >> 4;
        const int it = g & 15;
        o[g] = lds[ts * 16 + (it ^ (ts & 15))];
    }
}

extern "C" void kernel_launch(void* const* d_in, const int* in_sizes, int n_in,
                              void* d_out, int out_size, void* d_ws, size_t ws_size,
                              hipStream_t stream) {
    const float* x = (const float*)d_in[0];
    float* out = (float*)d_out;
    const int B  = in_sizes[0] / 48;  // 409600
    const int B4 = B / 4;             // 102400 threads
    const int threads = 128;
    const int blocks = B4 / threads;  // 800 exact (no tail; syncthreads-safe)
    gaussian_embed_kernel<<<blocks, threads, 0, stream>>>(x, out);
}